// Round 5
// baseline (161.460 us; speedup 1.0000x reference)
//
#include <hip/hip_runtime.h>

#define EPSV 1e-5f

// ---------------------------------------------------------------------------
// Kernel 1: fold the three branches into one 13x13 depthwise kernel + bias.
// ---------------------------------------------------------------------------
__global__ __launch_bounds__(256) void fuse_weights(
    const float* __restrict__ w_large, const float* __restrict__ w_small,
    const float* __restrict__ g_l, const float* __restrict__ b_l,
    const float* __restrict__ m_l, const float* __restrict__ v_l,
    const float* __restrict__ g_s, const float* __restrict__ b_s,
    const float* __restrict__ m_s, const float* __restrict__ v_s,
    const float* __restrict__ g_i, const float* __restrict__ b_i,
    const float* __restrict__ m_i, const float* __restrict__ v_i,
    float* __restrict__ wf, float* __restrict__ bf) {
    const int c = blockIdx.x;
    const int t = threadIdx.x;
    const float sl = g_l[c] * rsqrtf(v_l[c] + EPSV);
    const float ss = g_s[c] * rsqrtf(v_s[c] + EPSV);
    const float si = g_i[c] * rsqrtf(v_i[c] + EPSV);
    if (t < 169) {
        const int ky = t / 13, kx = t % 13;
        float w = w_large[c * 169 + t] * sl;
        if (ky >= 5 && ky <= 7 && kx >= 5 && kx <= 7)
            w += w_small[c * 9 + (ky - 5) * 3 + (kx - 5)] * ss;
        if (t == 6 * 13 + 6) w += si;
        wf[c * 169 + t] = w;
    }
    if (t == 0)
        bf[c] = (b_l[c] - m_l[c] * sl) + (b_s[c] - m_s[c] * ss) +
                (b_i[c] - m_i[c] * si);
}

// ---------------------------------------------------------------------------
// Kernel 2: depthwise 13x13 + bias, [16,384,64,64] f32. No LDS (0 conflicts);
// x read through L1. 256 threads/block = TWO images per block (half-block
// each; c is wave-uniform -> scalar weight loads). Thread (rg,cg) computes a
// 4x8 output block. Explicit 2-deep software pipeline: window buffers
// xwA/xwB, step-2 tap-row loop prefetching dr+1/dr+2 while computing dr/dr+1
// -> both windows live in regs (~100 VGPR), loads overlap FMA. Halo: invalid
// (row|col) chunks redirect base pointer to a zeroed 16KB image in ws.
// ---------------------------------------------------------------------------
__global__ __launch_bounds__(256, 4) void dwconv13(
    const float* __restrict__ x, const float* __restrict__ wf,
    const float* __restrict__ bf, const float* __restrict__ zimg,
    float* __restrict__ out) {
    const int t = threadIdx.x;            // 0..255
    const int half = t >> 7;              // 0/1 (wave-uniform)
    const int tl = t & 127;
    const int img = blockIdx.x * 2 + half;
    const int c = img % 384;
    const size_t base = (size_t)img * 4096;
    const int rg = tl >> 3;               // 0..15 -> rows 4*rg..4*rg+3
    const int cg = tl & 7;                // 0..7  -> cols 8*cg..8*cg+7
    const int r0 = rg << 2;
    const int c0 = cg << 3;

    const float* __restrict__ imgp = x + base;
    const float* __restrict__ wc = wf + c * 169;
    const float bv = bf[c];

    // loop-invariant per-chunk column info (window cols c0-8 .. c0+15)
    int cbc[6];
    bool colok[6];
#pragma unroll
    for (int q = 0; q < 6; ++q) {
        const int cb = c0 - 8 + 4 * q;           // -8..68, multiple of 4
        colok[q] = (cb >= 0) && (cb <= 60);
        cbc[q] = cb < 0 ? 0 : (cb > 60 ? 60 : cb);
    }

    float acc[4][8];
#pragma unroll
    for (int i = 0; i < 4; ++i)
#pragma unroll
        for (int j = 0; j < 8; ++j) acc[i][j] = bv;

#define LOADROW(buf_, dr_)                                              \
    {                                                                   \
        const int riy = r0 + (dr_) - 6;                                 \
        const bool rowok = (riy >= 0) && (riy < 64);                    \
        const int riyc = riy < 0 ? 0 : (riy > 63 ? 63 : riy);           \
        const int roff = riyc << 6;                                     \
        _Pragma("unroll") for (int q = 0; q < 6; ++q) {                 \
            const float* sp = (rowok && colok[q]) ? imgp : zimg;        \
            *(float4*)&buf_[4 * q] = *(const float4*)(sp + roff + cbc[q]); \
        }                                                               \
    }

#define TAPS(buf_, dr_)                                                 \
    {                                                                   \
        _Pragma("unroll") for (int i = 0; i < 4; ++i) {                 \
            const int ky = (dr_) - i;                                   \
            if (ky >= 0 && ky <= 12) {                                  \
                const float* wr = wc + ky * 13;                         \
                _Pragma("unroll") for (int dc = 0; dc < 13; ++dc) {     \
                    const float w = wr[dc];                             \
                    _Pragma("unroll") for (int j = 0; j < 8; ++j)       \
                        acc[i][j] = fmaf(buf_[j + dc + 2], w, acc[i][j]); \
                }                                                       \
            }                                                           \
        }                                                               \
    }

    float xwA[24], xwB[24];
    LOADROW(xwA, 0);
#pragma unroll 1
    for (int dr = 0; dr < 17; dr += 2) {
        LOADROW(xwB, dr + 1);
        TAPS(xwA, dr);
        LOADROW(xwA, dr + 2);
        TAPS(xwB, dr + 1);
    }
    TAPS(xwA, 18);

#undef LOADROW
#undef TAPS

    float* ob = out + base + (size_t)r0 * 64 + c0;
#pragma unroll
    for (int i = 0; i < 4; ++i) {
        *(float4*)(ob + i * 64) =
            make_float4(acc[i][0], acc[i][1], acc[i][2], acc[i][3]);
        *(float4*)(ob + i * 64 + 4) =
            make_float4(acc[i][4], acc[i][5], acc[i][6], acc[i][7]);
    }
}

// ---------------------------------------------------------------------------
extern "C" void kernel_launch(void* const* d_in, const int* in_sizes, int n_in,
                              void* d_out, int out_size, void* d_ws,
                              size_t ws_size, hipStream_t stream) {
    const float* x = (const float*)d_in[0];
    const float* w_large = (const float*)d_in[1];
    const float* w_small = (const float*)d_in[2];
    const float* g_l = (const float*)d_in[3];
    const float* b_l = (const float*)d_in[4];
    const float* m_l = (const float*)d_in[5];
    const float* v_l = (const float*)d_in[6];
    const float* g_s = (const float*)d_in[7];
    const float* b_s = (const float*)d_in[8];
    const float* m_s = (const float*)d_in[9];
    const float* v_s = (const float*)d_in[10];
    const float* g_i = (const float*)d_in[11];
    const float* b_i = (const float*)d_in[12];
    const float* m_i = (const float*)d_in[13];
    const float* v_i = (const float*)d_in[14];
    float* outp = (float*)d_out;

    float* wfp = (float*)d_ws;                  // 384*169 = 64896 floats
    float* bfp = wfp + 64896;                   // 384 floats -> ends at 65280
    float* zimg = wfp + 65280;                  // 4096 zero floats (16 KB)

    hipMemsetAsync(zimg, 0, 4096 * sizeof(float), stream);
    fuse_weights<<<384, 256, 0, stream>>>(w_large, w_small, g_l, b_l, m_l, v_l,
                                          g_s, b_s, m_s, v_s, g_i, b_i, m_i,
                                          v_i, wfp, bfp);
    dwconv13<<<8 * 384, 256, 0, stream>>>(x, wfp, bfp, zimg, outp);
}

// Round 7
// 107.138 us; speedup vs baseline: 1.5070x; 1.5070x over previous
//
#include <hip/hip_runtime.h>

#define EPSV 1e-5f

#if defined(__has_builtin)
#if __has_builtin(__builtin_amdgcn_fdot2)
#define HAS_FDOT2 1
#endif
#endif

typedef __fp16 half2v __attribute__((ext_vector_type(2)));

__device__ __forceinline__ half2v u32_as_h2(unsigned u) {
    union { unsigned u; half2v h; } cv;
    cv.u = u;
    return cv.h;
}

// ---------------------------------------------------------------------------
// Kernel 1: fold the 3 branches into one 13x13 kernel + bias. Emits BOTH the
// f32 kernel (wf, fallback path) and f16-packed weight pairs (wpk): per
// channel, per tap-row ky: 7 u32s = half2(w[2k], w[2k+1]) with w[13]=0.
// ---------------------------------------------------------------------------
__global__ __launch_bounds__(256) void fuse_weights(
    const float* __restrict__ w_large, const float* __restrict__ w_small,
    const float* __restrict__ g_l, const float* __restrict__ b_l,
    const float* __restrict__ m_l, const float* __restrict__ v_l,
    const float* __restrict__ g_s, const float* __restrict__ b_s,
    const float* __restrict__ m_s, const float* __restrict__ v_s,
    const float* __restrict__ g_i, const float* __restrict__ b_i,
    const float* __restrict__ m_i, const float* __restrict__ v_i,
    float* __restrict__ wf, float* __restrict__ bf,
    unsigned* __restrict__ wpk) {
    __shared__ float sw[169];
    const int c = blockIdx.x;
    const int t = threadIdx.x;
    const float sl = g_l[c] * rsqrtf(v_l[c] + EPSV);
    const float ss = g_s[c] * rsqrtf(v_s[c] + EPSV);
    const float si = g_i[c] * rsqrtf(v_i[c] + EPSV);
    if (t < 169) {
        const int ky = t / 13, kx = t % 13;
        float w = w_large[c * 169 + t] * sl;
        if (ky >= 5 && ky <= 7 && kx >= 5 && kx <= 7)
            w += w_small[c * 9 + (ky - 5) * 3 + (kx - 5)] * ss;
        if (t == 6 * 13 + 6) w += si;
        wf[c * 169 + t] = w;
        sw[t] = w;
    }
    if (t == 0)
        bf[c] = (b_l[c] - m_l[c] * sl) + (b_s[c] - m_s[c] * ss) +
                (b_i[c] - m_i[c] * si);
    __syncthreads();
    if (t < 91) {  // 13 rows x 7 pairs
        const int ky = t / 7, k2 = t % 7;
        const float w0 = sw[ky * 13 + 2 * k2];
        const float w1 = (2 * k2 + 1 < 13) ? sw[ky * 13 + 2 * k2 + 1] : 0.0f;
        const half2v h = __builtin_amdgcn_cvt_pkrtz(w0, w1);
        union { half2v h; unsigned u; } cv;
        cv.h = h;
        wpk[c * 91 + t] = cv.u;
    }
}

// ---------------------------------------------------------------------------
// Kernel 2: depthwise 13x13 + bias, [16,384,64,64] f32. No LDS. 128 thr/blk,
// one image per block (L1-resident). Thread (rg=t>>3,cg=t&7) -> 4x8 outputs.
// Per input row (19): 6 global dwordx4, halo handled by 64-bit pointer
// cndmask to a zero row (valid = rowok & colok[q], SALU-combined). Window
// repacked to f16 pairs (even/odd phase) via v_cvt_pkrtz; inner product uses
// v_dot2_f32_f16 (2 MACs/instr, f32 accum): 7 dot2 per (row, out-col).
// ---------------------------------------------------------------------------
__global__ __launch_bounds__(128, 5) void dwconv13(
    const float* __restrict__ x, const float* __restrict__ wff,
    const unsigned* __restrict__ wpk, const float* __restrict__ bf,
    const float* __restrict__ zrow, float* __restrict__ out) {
    const int t = threadIdx.x;           // 0..127
    const int img = blockIdx.x;          // n*384 + c
    const int c = __builtin_amdgcn_readfirstlane(img % 384);
    const size_t base = (size_t)img * 4096;
    const int rg = t >> 3;               // 0..15 -> rows 4*rg..4*rg+3
    const int cg = t & 7;                // 0..7  -> cols 8*cg..8*cg+7
    const int r0 = rg << 2;
    const int c0 = cg << 3;

    const float* __restrict__ imgp = x + base;
    const float bv = bf[c];

    // loop-invariant per-chunk column offsets/validity (window c0-8..c0+15)
    int cb[6];
    bool colok[6];
#pragma unroll
    for (int q = 0; q < 6; ++q) {
        const int cbv = c0 - 8 + 4 * q;          // -8..68
        colok[q] = (cbv >= 0) && (cbv <= 60);
        cb[q] = cbv;
    }

    float acc[4][8];
#pragma unroll
    for (int i = 0; i < 4; ++i)
#pragma unroll
        for (int j = 0; j < 8; ++j) acc[i][j] = bv;

#ifdef HAS_FDOT2
    const unsigned* __restrict__ wc = wpk + c * 91;
    half2v ep[11], op[11];               // even/odd phase pairs, use [1..10]
#else
    const float* __restrict__ wc = wff + c * 169;
#endif

#pragma unroll 1
    for (int dr = 0; dr < 19; ++dr) {
        const int riy = r0 + dr - 6;             // -6..72
        const bool rowok = ((unsigned)riy) < 64u;
        const float* rb = imgp + (riy << 6);     // bogus if !rowok (unselected)

        float xf[24];
#pragma unroll
        for (int q = 0; q < 6; ++q) {
            const float* p = (rowok && colok[q]) ? (rb + cb[q]) : zrow;
            const float4 v = *(const float4*)p;
            xf[4 * q + 0] = v.x;
            xf[4 * q + 1] = v.y;
            xf[4 * q + 2] = v.z;
            xf[4 * q + 3] = v.w;
        }

#ifdef HAS_FDOT2
#pragma unroll
        for (int k = 1; k <= 10; ++k) {
            ep[k] = __builtin_amdgcn_cvt_pkrtz(xf[2 * k], xf[2 * k + 1]);
            op[k] = __builtin_amdgcn_cvt_pkrtz(xf[2 * k + 1], xf[2 * k + 2]);
        }
#pragma unroll
        for (int i = 0; i < 4; ++i) {
            const int ky = dr - i;               // wave-uniform
            if (ky >= 0 && ky <= 12) {
                const unsigned* wr = wc + ky * 7;
#pragma unroll
                for (int j = 0; j < 8; ++j) {
                    const int b = (j >> 1) + 1;
                    float a = acc[i][j];
                    if (j & 1) {
#pragma unroll
                        for (int k = 0; k < 7; ++k)
                            a = __builtin_amdgcn_fdot2(op[b + k],
                                                       u32_as_h2(wr[k]), a,
                                                       false);
                    } else {
#pragma unroll
                        for (int k = 0; k < 7; ++k)
                            a = __builtin_amdgcn_fdot2(ep[b + k],
                                                       u32_as_h2(wr[k]), a,
                                                       false);
                    }
                    acc[i][j] = a;
                }
            }
        }
#else
#pragma unroll
        for (int i = 0; i < 4; ++i) {
            const int ky = dr - i;
            if (ky >= 0 && ky <= 12) {
                const float* wr = wc + ky * 13;
#pragma unroll
                for (int dc = 0; dc < 13; ++dc) {
                    const float w = wr[dc];
#pragma unroll
                    for (int j = 0; j < 8; ++j)
                        acc[i][j] = fmaf(xf[j + dc + 2], w, acc[i][j]);
                }
            }
        }
#endif
    }

    float* ob = out + base + (size_t)r0 * 64 + c0;
#pragma unroll
    for (int i = 0; i < 4; ++i) {
        *(float4*)(ob + i * 64) =
            make_float4(acc[i][0], acc[i][1], acc[i][2], acc[i][3]);
        *(float4*)(ob + i * 64 + 4) =
            make_float4(acc[i][4], acc[i][5], acc[i][6], acc[i][7]);
    }
}

// ---------------------------------------------------------------------------
extern "C" void kernel_launch(void* const* d_in, const int* in_sizes, int n_in,
                              void* d_out, int out_size, void* d_ws,
                              size_t ws_size, hipStream_t stream) {
    const float* x = (const float*)d_in[0];
    const float* w_large = (const float*)d_in[1];
    const float* w_small = (const float*)d_in[2];
    const float* g_l = (const float*)d_in[3];
    const float* b_l = (const float*)d_in[4];
    const float* m_l = (const float*)d_in[5];
    const float* v_l = (const float*)d_in[6];
    const float* g_s = (const float*)d_in[7];
    const float* b_s = (const float*)d_in[8];
    const float* m_s = (const float*)d_in[9];
    const float* v_s = (const float*)d_in[10];
    const float* g_i = (const float*)d_in[11];
    const float* b_i = (const float*)d_in[12];
    const float* m_i = (const float*)d_in[13];
    const float* v_i = (const float*)d_in[14];
    float* outp = (float*)d_out;

    // ws layout (floats): zimg[4096] | wf[64896] | bf[384] | wpk[34944 u32]
    float* zimg = (float*)d_ws;
    float* wfp = zimg + 4096;
    float* bfp = wfp + 64896;
    unsigned* wpk = (unsigned*)(bfp + 384);

    (void)hipMemsetAsync(zimg, 0, 4096 * sizeof(float), stream);
    fuse_weights<<<384, 256, 0, stream>>>(w_large, w_small, g_l, b_l, m_l, v_l,
                                          g_s, b_s, m_s, v_s, g_i, b_i, m_i,
                                          v_i, wfp, bfp, wpk);
    dwconv13<<<16 * 384, 128, 0, stream>>>(x, wfp, wpk, bfp, zimg, outp);
}